// Round 10
// baseline (1978.018 us; speedup 1.0000x reference)
//
#include <hip/hip_runtime.h>
#include <cstddef>

#define NROWS 16384
#define NE    8192
#define DD    256
#define TM    256
#define TN    128
#define BK    16
#define NCH   8
#define CHW   (NE / NCH)   // 1024 cols per chunk

typedef unsigned long long u64;
typedef float vf4 __attribute__((ext_vector_type(4)));
typedef float vf2 __attribute__((ext_vector_type(2)));

#define OH_TOT ((size_t)NROWS * NE)           // 134217728 floats
#define OH_VEC ((OH_TOT - 4) / 4)             // 33554431 aligned vf4 slots

// ---------------------------------------------------------------------------
// k_rowsq: zsq[n] = sum(z[n,:]^2) in numpy pairwise order (256 = 128+128,
// each 128-block via 8 strided accumulators r[j] += x[8i+j]^2, combined
// pairwise). float4 loads (same add order as scalar). Also inits best[],
// counts.
// ---------------------------------------------------------------------------
__global__ __launch_bounds__(256) void k_rowsq(
    const float* __restrict__ z, const float* __restrict__ emb,
    float* __restrict__ zsq, float* __restrict__ esq,
    u64* __restrict__ best, int* __restrict__ counts)
{
  const int g = blockIdx.x * 256 + threadIdx.x;   // 0 .. 24575
  if (g < NE) counts[g] = 0;
  if (g < NROWS) best[g] = ~0ull;

  const float* row;
  float* outp;
  if (g < NROWS) { row = z + (size_t)g * DD;            outp = zsq + g; }
  else           { row = emb + (size_t)(g - NROWS) * DD; outp = esq + (g - NROWS); }

  float half_s[2];
#pragma unroll
  for (int h = 0; h < 2; ++h) {
    const float* p = row + h * 128;
    float r[8];
    {
      const float4 v0 = *(const float4*)(p);
      const float4 v1 = *(const float4*)(p + 4);
      const float xs[8] = {v0.x, v0.y, v0.z, v0.w, v1.x, v1.y, v1.z, v1.w};
#pragma unroll
      for (int j = 0; j < 8; ++j) {
        float sq = xs[j] * xs[j];
        asm volatile("" : "+v"(sq));   // block FMA contraction: np rounds x*x first
        r[j] = sq;
      }
    }
    for (int i = 8; i < 128; i += 8) {
      const float4 v0 = *(const float4*)(p + i);
      const float4 v1 = *(const float4*)(p + i + 4);
      const float xs[8] = {v0.x, v0.y, v0.z, v0.w, v1.x, v1.y, v1.z, v1.w};
#pragma unroll
      for (int j = 0; j < 8; ++j) {
        float sq = xs[j] * xs[j];
        asm volatile("" : "+v"(sq));
        r[j] = r[j] + sq;
      }
    }
    half_s[h] = ((r[0] + r[1]) + (r[2] + r[3])) + ((r[4] + r[5]) + (r[6] + r[7]));
  }
  *outp = half_s[0] + half_s[1];
}

// ---------------------------------------------------------------------------
// k_argmin v8: A-operand now read DIRECTLY from global (L1-broadcast: each
// address shared by the 16 lanes of a tx-group; 16-k phase working set is
// 16 KB = L1-resident; k-byte-offset fits the load immediate so row voffsets
// are loop-invariant). LDS carries only B: per-kk LDS demand drops 96->32 B
// per thread (0.75 -> 0.25 B/FLOP), under the ~128 B/cyc/CU LDS ceiling that
// capped rounds 3-9 at 66% VALUBusy. A values are bit-identical to the LDS
// path and the per-(row,col) ascending-k FMA chain is unchanged -> argmin
// decisions bit-exact vs rounds 1-9. Fused nt one-hot zero-fill, u64-packed
// atomicMin, vf2 pk-fma accumulators all unchanged.
// ---------------------------------------------------------------------------
__global__ __launch_bounds__(256)
__attribute__((amdgpu_waves_per_eu(2, 2)))
void k_argmin(
    const float* __restrict__ z, const float* __restrict__ emb,
    const float* __restrict__ zsq, const float* __restrict__ esq,
    u64* __restrict__ best, float* __restrict__ ohbase)
{
  __shared__ float Bs[2][BK][TN];       // 16 KB total (B only; A no longer staged)

  const int tid = threadIdx.x;
  const int tx = tid & 15;
  const int ty = tid >> 4;
  const int tx4 = tx * 4;
  const int ty4 = ty * 4;
  const int R0 = blockIdx.x * TM;
  const int C0 = blockIdx.y * CHW;

  const int bcol = tid & 127;           // B staging col
  const int bk8  = (tid >> 7) * 8;      // B staging k-offset (0 or 8)

  // loop-invariant element offsets of this thread's 16 A-rows
  int rofs[16];
#pragma unroll
  for (int i = 0; i < 16; ++i)
    rofs[i] = (R0 + 64 * (i >> 2) + ty4 + (i & 3)) * DD;

  // one-hot zero-fill state: flat block id owns vf4 slots [b*65536,(b+1)*65536)
  const int bflat = blockIdx.y * (NROWS / TM) + blockIdx.x;   // 0..511
  size_t zt = (size_t)bflat * 65536 + tid;                    // step 256, x256
  float* zp = ohbase + 2;                                     // 16B-aligned
  const vf4 zzero = {0.0f, 0.0f, 0.0f, 0.0f};
  if (bflat == 0 && tid == 0) { ohbase[0] = 0.0f; ohbase[1] = 0.0f; }
  if (bflat == 511 && tid == 0) { ohbase[OH_TOT - 2] = 0.0f; ohbase[OH_TOT - 1] = 0.0f; }

  u64 bp[16];
#pragma unroll
  for (int i = 0; i < 16; ++i) bp[i] = ~0ull;

#define STAGE_B(B_, K_)                                                   \
  {                                                                       \
    _Pragma("unroll")                                                     \
    for (int h = 0; h < 2; ++h) {                                         \
      const float4 v = *(const float4*)(ecol + (K_) + 4 * h);             \
      Bs[B_][bk8 + 4 * h + 0][bcol] = v.x;                                \
      Bs[B_][bk8 + 4 * h + 1][bcol] = v.y;                                \
      Bs[B_][bk8 + 4 * h + 2][bcol] = v.z;                                \
      Bs[B_][bk8 + 4 * h + 3][bcol] = v.w;                                \
    }                                                                     \
    if (zt < OH_VEC) __builtin_nontemporal_store(zzero, (vf4*)(zp + 4 * zt)); \
    zt += 256;                                                            \
    if (zt < OH_VEC) __builtin_nontemporal_store(zzero, (vf4*)(zp + 4 * zt)); \
    zt += 256;                                                            \
  }

  // one 16-k chunk: 4 batches of 4 k; A via global float4 (4 k each row)
#define COMPUTE(B_, KG_)                                                  \
  _Pragma("unroll 2")                                                     \
  for (int b = 0; b < 4; ++b) {                                           \
    const int kg = (KG_) + 4 * b;                                         \
    float4 va[16];                                                        \
    _Pragma("unroll")                                                     \
    for (int i = 0; i < 16; ++i)                                          \
      va[i] = *(const float4*)(z + rofs[i] + kg);                         \
    _Pragma("unroll")                                                     \
    for (int kk = 0; kk < 4; ++kk) {                                      \
      const int kl = 4 * b + kk;                                          \
      const float4 b0 = *(const float4*)(&Bs[B_][kl][tx4]);               \
      const float4 b1 = *(const float4*)(&Bs[B_][kl][tx4 + 64]);          \
      const vf2 p0 = {b0.x, b0.y}, p1 = {b0.z, b0.w};                     \
      const vf2 p2 = {b1.x, b1.y}, p3 = {b1.z, b1.w};                     \
      _Pragma("unroll")                                                   \
      for (int i = 0; i < 16; ++i) {                                      \
        const float a = (kk == 0) ? va[i].x : (kk == 1) ? va[i].y         \
                        : (kk == 2) ? va[i].z : va[i].w;                  \
        const vf2 a2v = {a, a};                                           \
        acc[i][0] = __builtin_elementwise_fma(a2v, p0, acc[i][0]);        \
        acc[i][1] = __builtin_elementwise_fma(a2v, p1, acc[i][1]);        \
        acc[i][2] = __builtin_elementwise_fma(a2v, p2, acc[i][2]);        \
        acc[i][3] = __builtin_elementwise_fma(a2v, p3, acc[i][3]);        \
      }                                                                   \
    }                                                                     \
  }

  for (int t = 0; t < CHW; t += TN) {
    const int Cb = C0 + t;
    const float* ecol = emb + (size_t)(Cb + bcol) * DD + bk8;

    vf2 acc[16][4];   // [i][j2]: j2=0,1 -> cols tx4+0..3 ; j2=2,3 -> tx4+64..67
#pragma unroll
    for (int i = 0; i < 16; ++i)
#pragma unroll
      for (int j = 0; j < 4; ++j) acc[i][j] = (vf2){0.0f, 0.0f};

    STAGE_B(0, 0);
    __syncthreads();
    for (int c = 0; c < 16; c += 2) {
      if (c + 1 < 16) STAGE_B(1, (c + 1) * BK);
      COMPUTE(0, c * BK);
      __syncthreads();
      if (c + 2 < 16) STAGE_B(0, (c + 2) * BK);
      COMPUTE(1, (c + 1) * BK);
      __syncthreads();
    }

#pragma unroll
    for (int j = 0; j < 8; ++j) {
      const int col = Cb + tx4 + ((j < 4) ? j : 64 + j - 4);
      const float ev = esq[col];
#pragma unroll
      for (int i = 0; i < 16; ++i) {
        const float zri = zsq[R0 + (i >> 2) * 64 + ty4 + (i & 3)];
        const float aij = acc[i][j >> 1][j & 1];
        const float s1 = zri + ev;                // fl(zsq+esq), matches np
        const float dv = s1 - 2.0f * aij;         // fl(s1 - 2*dot); 2*dot exact
        const u64 p = ((u64)__float_as_uint(dv) << 32) | (unsigned)col;
        if (p < bp[i]) bp[i] = p;
      }
    }
  }

#pragma unroll
  for (int i = 0; i < 16; ++i) {
#pragma unroll
    for (int off = 8; off > 0; off >>= 1) {
      const u64 o = __shfl_xor(bp[i], off, 16);
      if (o < bp[i]) bp[i] = o;
    }
  }
  if (tx == 0) {
#pragma unroll
    for (int i = 0; i < 16; ++i) {
      const int r = R0 + (i >> 2) * 64 + ty4 + (i & 3);
      atomicMin(&best[r], bp[i]);
    }
  }
}

// ---------------------------------------------------------------------------
// k_gather2: 4 rows per block. z_q gather, one-hot 1.0 scatter (zeros were
// laid down by k_argmin), float(index), counts, per-block loss partial.
// ---------------------------------------------------------------------------
__global__ __launch_bounds__(256) void k_gather2(
    const float* __restrict__ z, const float* __restrict__ emb,
    const u64* __restrict__ best,
    float* __restrict__ out_zq, float* __restrict__ out_onehot,
    float* __restrict__ out_idx, float* __restrict__ partials,
    int* __restrict__ counts)
{
  __shared__ float sred[256];
  const int row = blockIdx.x * 4 + (threadIdx.x >> 6);
  const int lane = threadIdx.x & 63;
  const int idx = (int)(unsigned)(best[row] & 0xffffffffull);
  const int k0 = lane * 4;

  const float4 e  = *(const float4*)(emb + (size_t)idx * DD + k0);
  const float4 zv = *(const float4*)(z + (size_t)row * DD + k0);
  *(float4*)(out_zq + (size_t)row * DD + k0) = e;

  const float dx = e.x - zv.x, dy = e.y - zv.y, dz = e.z - zv.z, dw = e.w - zv.w;
  sred[threadIdx.x] = dx * dx + dy * dy + dz * dz + dw * dw;

  if (lane == 0) {
    out_idx[row] = (float)idx;
    out_onehot[(size_t)row * NE + idx] = 1.0f;
    atomicAdd(&counts[idx], 1);
  }
  __syncthreads();
  for (int s = 128; s > 0; s >>= 1) {
    if (threadIdx.x < s) sred[threadIdx.x] += sred[threadIdx.x + s];
    __syncthreads();
  }
  if (threadIdx.x == 0) partials[blockIdx.x] = sred[0];
}

// ---------------------------------------------------------------------------
// k_final: loss = 1.25 * sum(partials) / (N*D); perplexity from counts.
// ---------------------------------------------------------------------------
__global__ __launch_bounds__(256) void k_final(
    const int* __restrict__ counts, const float* __restrict__ partials,
    float* __restrict__ out_loss, float* __restrict__ out_perp)
{
  __shared__ float sred[256];
  __shared__ float sl[256];
  float le = 0.0f;
  for (int e = threadIdx.x; e < NE; e += 256) {
    const float p = (float)counts[e] * (1.0f / 16384.0f);
    le += p * logf(p + 1e-10f);
  }
  float ll = 0.0f;
  for (int b = threadIdx.x; b < NROWS / 4; b += 256) ll += partials[b];
  sred[threadIdx.x] = le;
  sl[threadIdx.x] = ll;
  __syncthreads();
  for (int s = 128; s > 0; s >>= 1) {
    if (threadIdx.x < s) {
      sred[threadIdx.x] += sred[threadIdx.x + s];
      sl[threadIdx.x] += sl[threadIdx.x + s];
    }
    __syncthreads();
  }
  if (threadIdx.x == 0) {
    *out_perp = expf(-sred[0]);
    *out_loss = sl[0] * (1.25f / 4194304.0f);  // (1+beta) * sum / (N*D)
  }
}

// ---------------------------------------------------------------------------
// Output layout (float32, concatenated in reference return order):
//   [0]                loss                       (1)
//   [1 .. 4194304]     z_q_st                     (16384*256)
//   [4194305]          perplexity                 (1)
//   [4194306 ..]       min_encodings one-hot      (16384*8192)
//   [138412034 ..]     min_encoding_indices       (16384, written as float)
// ---------------------------------------------------------------------------
extern "C" void kernel_launch(void* const* d_in, const int* in_sizes, int n_in,
                              void* d_out, int out_size, void* d_ws, size_t ws_size,
                              hipStream_t stream) {
  const float* z   = (const float*)d_in[0];
  const float* emb = (const float*)d_in[1];

  float* out        = (float*)d_out;
  float* out_loss   = out;
  float* out_zq     = out + 1;
  float* out_perp   = out + 4194305;
  float* out_onehot = out + 4194306;
  float* out_idx    = out + 138412034;

  float* zsq      = (float*)d_ws;            // 16384 f
  float* esq      = zsq + NROWS;             // 8192 f
  u64*   best     = (u64*)(esq + NE);        // 16384 u64 (8B-aligned: offset 96 KB)
  int*   counts   = (int*)(best + NROWS);    // 8192 int
  float* partials = (float*)(counts + NE);   // 4096 f

  k_rowsq<<<96, 256, 0, stream>>>(z, emb, zsq, esq, best, counts);
  k_argmin<<<dim3(NROWS / TM, NCH), 256, 0, stream>>>(z, emb, zsq, esq, best,
                                                      out_onehot);
  k_gather2<<<NROWS / 4, 256, 0, stream>>>(z, emb, best, out_zq, out_onehot,
                                           out_idx, partials, counts);
  k_final<<<1, 256, 0, stream>>>(counts, partials, out_loss, out_perp);
}

// Round 11
// 1642.102 us; speedup vs baseline: 1.2046x; 1.2046x over previous
//
#include <hip/hip_runtime.h>
#include <cstddef>

#define NROWS 16384
#define NE    8192
#define DD    256
#define TMW   16                   // rows per wave
#define TM    64                   // rows per block (4 waves)
#define TN    128                  // cols per t-tile
#define BK    32                   // k per LDS chunk
#define NCH   4
#define CHW   (NE / NCH)           // 2048 cols per chunk
#define NT    (CHW / TN)           // 16 t-tiles per block

typedef unsigned long long u64;
typedef float vf4 __attribute__((ext_vector_type(4)));

#define OH_TOT ((size_t)NROWS * NE)          // 134217728 floats
#define OH_VEC ((OH_TOT - 4) / 4)            // 33554431 aligned vf4 slots

// ---------------------------------------------------------------------------
// k_rowsq: zsq[n] = sum(z[n,:]^2) in numpy pairwise order. Inits best/counts.
// ---------------------------------------------------------------------------
__global__ __launch_bounds__(256) void k_rowsq(
    const float* __restrict__ z, const float* __restrict__ emb,
    float* __restrict__ zsq, float* __restrict__ esq,
    u64* __restrict__ best, int* __restrict__ counts)
{
  const int g = blockIdx.x * 256 + threadIdx.x;   // 0 .. 24575
  if (g < NE) counts[g] = 0;
  if (g < NROWS) best[g] = ~0ull;

  const float* row;
  float* outp;
  if (g < NROWS) { row = z + (size_t)g * DD;            outp = zsq + g; }
  else           { row = emb + (size_t)(g - NROWS) * DD; outp = esq + (g - NROWS); }

  float half_s[2];
#pragma unroll
  for (int h = 0; h < 2; ++h) {
    const float* p = row + h * 128;
    float r[8];
    {
      const float4 v0 = *(const float4*)(p);
      const float4 v1 = *(const float4*)(p + 4);
      const float xs[8] = {v0.x, v0.y, v0.z, v0.w, v1.x, v1.y, v1.z, v1.w};
#pragma unroll
      for (int j = 0; j < 8; ++j) {
        float sq = xs[j] * xs[j];
        asm volatile("" : "+v"(sq));   // np rounds x*x before the add
        r[j] = sq;
      }
    }
    for (int i = 8; i < 128; i += 8) {
      const float4 v0 = *(const float4*)(p + i);
      const float4 v1 = *(const float4*)(p + i + 4);
      const float xs[8] = {v0.x, v0.y, v0.z, v0.w, v1.x, v1.y, v1.z, v1.w};
#pragma unroll
      for (int j = 0; j < 8; ++j) {
        float sq = xs[j] * xs[j];
        asm volatile("" : "+v"(sq));
        r[j] = r[j] + sq;
      }
    }
    half_s[h] = ((r[0] + r[1]) + (r[2] + r[3])) + ((r[4] + r[5]) + (r[6] + r[7]));
  }
  *outp = half_s[0] + half_s[1];
}

// ---------------------------------------------------------------------------
// k_argmin v9: wave-uniform-A design. Each wave owns 16 rows; all 64 lanes
// share them, so A loads are wave-uniform (SGPR/scalar-cache path — LDS no
// longer carries A). Lane owns cols lane and lane+64 of each 128-col t-tile;
// B staged in LDS [k][col] (b32 reads, 2-way bank aliasing = free). LDS
// demand drops 96 -> 8 B/lane/kk — removes the 67% VALU cap measured in
// R5-R9. acc 32 + bp 32 regs -> ~4 waves/SIMD, 4 blocks/CU (Bs 32 KB).
// Numerics: ascending-k fused-FMA chain per (row,col), dv = fl(fl(zsq+esq)
// - 2*dot), u64 (bits(dv)<<32)|col atomicMin — bit-identical to rounds 1-9.
// Fused nt one-hot zero-fill: exactly 128 stores/thread over 128 stages.
// ---------------------------------------------------------------------------
__global__ __launch_bounds__(256)
void k_argmin(
    const float* __restrict__ z, const float* __restrict__ emb,
    const float* __restrict__ zsq, const float* __restrict__ esq,
    u64* __restrict__ best, float* __restrict__ ohbase)
{
  __shared__ float Bs[2][BK][TN];      // 32 KB

  const int tid = threadIdx.x;
  const int lane = tid & 63;
  const int wid = __builtin_amdgcn_readfirstlane(tid >> 6);
  const int R0 = blockIdx.x * TM + wid * TMW;
  const int C0 = blockIdx.y * CHW;

  const float* zw = z + (size_t)R0 * DD;          // wave-uniform base

  float zr[16];                                    // uniform -> SGPRs
#pragma unroll
  for (int r = 0; r < 16; ++r) zr[r] = zsq[R0 + r];

  const int scol = tid >> 1;                       // B staging col (0..127)
  const int skh  = (tid & 1) * 16;                 // B staging k-half

  const int bflat = blockIdx.y * 256 + blockIdx.x; // gridDim.x == 256
  size_t zt = (size_t)bflat * 32768 + tid;         // 128 stores/thread
  float* zp = ohbase + 2;                          // 16B-aligned interior
  const vf4 zzero = {0.0f, 0.0f, 0.0f, 0.0f};
  if (bflat == 0 && tid == 0) { ohbase[0] = 0.0f; ohbase[1] = 0.0f; }
  if (bflat == 1023 && tid == 0) { ohbase[OH_TOT - 2] = 0.0f; ohbase[OH_TOT - 1] = 0.0f; }

  u64 bp[16];
#pragma unroll
  for (int r = 0; r < 16; ++r) bp[r] = ~0ull;

#define STAGE(B_, KC_, CB_)                                               \
  {                                                                       \
    const float* ecol = emb + (size_t)((CB_) + scol) * DD + (KC_) * BK + skh; \
    _Pragma("unroll")                                                     \
    for (int q = 0; q < 4; ++q) {                                         \
      const vf4 v = *(const vf4*)(ecol + 4 * q);                          \
      _Pragma("unroll")                                                   \
      for (int j = 0; j < 4; ++j) Bs[B_][skh + 4 * q + j][scol] = v[j];   \
    }                                                                     \
    if (zt < OH_VEC) __builtin_nontemporal_store(zzero, (vf4*)(zp + 4 * zt)); \
    zt += 256;                                                            \
  }

#define COMPUTE(B_, KC_)                                                  \
  {                                                                       \
    _Pragma("unroll 2")                                                   \
    for (int g = 0; g < 8; ++g) {                                         \
      vf4 a4[16];                                                         \
      _Pragma("unroll")                                                   \
      for (int r = 0; r < 16; ++r)                                        \
        a4[r] = *(const vf4*)(zw + r * DD + (KC_) * BK + 4 * g);          \
      _Pragma("unroll")                                                   \
      for (int kk = 0; kk < 4; ++kk) {                                    \
        const float bAv = Bs[B_][4 * g + kk][lane];                       \
        const float bBv = Bs[B_][4 * g + kk][lane + 64];                  \
        _Pragma("unroll")                                                 \
        for (int r = 0; r < 16; ++r) {                                    \
          accA[r] = fmaf(a4[r][kk], bAv, accA[r]);                        \
          accB[r] = fmaf(a4[r][kk], bBv, accB[r]);                        \
        }                                                                 \
      }                                                                   \
    }                                                                     \
  }

  for (int t = 0; t < NT; ++t) {
    const int Cb = C0 + t * TN;
    const float evA = esq[Cb + lane];
    const float evB = esq[Cb + lane + 64];
    float accA[16], accB[16];
#pragma unroll
    for (int r = 0; r < 16; ++r) { accA[r] = 0.0f; accB[r] = 0.0f; }

    STAGE(0, 0, Cb);
    __syncthreads();
    for (int kc = 0; kc < 8; kc += 2) {
      if (kc + 1 < 8) STAGE(1, kc + 1, Cb);
      COMPUTE(0, kc);
      __syncthreads();
      if (kc + 2 < 8) STAGE(0, kc + 2, Cb);
      COMPUTE(1, kc + 1);
      __syncthreads();
    }

    const int colA = Cb + lane;
    const int colB = Cb + lane + 64;
#pragma unroll
    for (int r = 0; r < 16; ++r) {
      float s1 = zr[r] + evA;                 // fl(zsq+esq), matches np
      float dv = s1 - 2.0f * accA[r];         // fl(s1 - 2*dot); 2*dot exact
      u64 p = ((u64)__float_as_uint(dv) << 32) | (unsigned)colA;
      if (p < bp[r]) bp[r] = p;
      s1 = zr[r] + evB;
      dv = s1 - 2.0f * accB[r];
      p = ((u64)__float_as_uint(dv) << 32) | (unsigned)colB;
      if (p < bp[r]) bp[r] = p;
    }
  }

  // reduce each row's best across the 64 lanes of the wave
#pragma unroll
  for (int r = 0; r < 16; ++r) {
#pragma unroll
    for (int off = 32; off > 0; off >>= 1) {
      const u64 o = __shfl_xor(bp[r], off, 64);
      if (o < bp[r]) bp[r] = o;
    }
  }
  if (lane == 0) {
#pragma unroll
    for (int r = 0; r < 16; ++r) atomicMin(&best[R0 + r], bp[r]);
  }
}

// ---------------------------------------------------------------------------
// k_gather2: 4 rows per block. z_q gather, one-hot 1.0 scatter (zeros laid
// down by k_argmin), float(index), counts, per-block loss partial.
// ---------------------------------------------------------------------------
__global__ __launch_bounds__(256) void k_gather2(
    const float* __restrict__ z, const float* __restrict__ emb,
    const u64* __restrict__ best,
    float* __restrict__ out_zq, float* __restrict__ out_onehot,
    float* __restrict__ out_idx, float* __restrict__ partials,
    int* __restrict__ counts)
{
  __shared__ float sred[256];
  const int row = blockIdx.x * 4 + (threadIdx.x >> 6);
  const int lane = threadIdx.x & 63;
  const int idx = (int)(unsigned)(best[row] & 0xffffffffull);
  const int k0 = lane * 4;

  const float4 e  = *(const float4*)(emb + (size_t)idx * DD + k0);
  const float4 zv = *(const float4*)(z + (size_t)row * DD + k0);
  *(float4*)(out_zq + (size_t)row * DD + k0) = e;

  const float dx = e.x - zv.x, dy = e.y - zv.y, dz = e.z - zv.z, dw = e.w - zv.w;
  sred[threadIdx.x] = dx * dx + dy * dy + dz * dz + dw * dw;

  if (lane == 0) {
    out_idx[row] = (float)idx;
    out_onehot[(size_t)row * NE + idx] = 1.0f;
    atomicAdd(&counts[idx], 1);
  }
  __syncthreads();
  for (int s = 128; s > 0; s >>= 1) {
    if (threadIdx.x < s) sred[threadIdx.x] += sred[threadIdx.x + s];
    __syncthreads();
  }
  if (threadIdx.x == 0) partials[blockIdx.x] = sred[0];
}

// ---------------------------------------------------------------------------
// k_final: loss = 1.25 * sum(partials) / (N*D); perplexity from counts.
// ---------------------------------------------------------------------------
__global__ __launch_bounds__(256) void k_final(
    const int* __restrict__ counts, const float* __restrict__ partials,
    float* __restrict__ out_loss, float* __restrict__ out_perp)
{
  __shared__ float sred[256];
  __shared__ float sl[256];
  float le = 0.0f;
  for (int e = threadIdx.x; e < NE; e += 256) {
    const float p = (float)counts[e] * (1.0f / 16384.0f);
    le += p * logf(p + 1e-10f);
  }
  float ll = 0.0f;
  for (int b = threadIdx.x; b < NROWS / 4; b += 256) ll += partials[b];
  sred[threadIdx.x] = le;
  sl[threadIdx.x] = ll;
  __syncthreads();
  for (int s = 128; s > 0; s >>= 1) {
    if (threadIdx.x < s) {
      sred[threadIdx.x] += sred[threadIdx.x + s];
      sl[threadIdx.x] += sl[threadIdx.x + s];
    }
    __syncthreads();
  }
  if (threadIdx.x == 0) {
    *out_perp = expf(-sred[0]);
    *out_loss = sl[0] * (1.25f / 4194304.0f);  // (1+beta) * sum / (N*D)
  }
}

// ---------------------------------------------------------------------------
// Output layout (float32, concatenated in reference return order):
//   [0]                loss                       (1)
//   [1 .. 4194304]     z_q_st                     (16384*256)
//   [4194305]          perplexity                 (1)
//   [4194306 ..]       min_encodings one-hot      (16384*8192)
//   [138412034 ..]     min_encoding_indices       (16384, written as float)
// ---------------------------------------------------------------------------
extern "C" void kernel_launch(void* const* d_in, const int* in_sizes, int n_in,
                              void* d_out, int out_size, void* d_ws, size_t ws_size,
                              hipStream_t stream) {
  const float* z   = (const float*)d_in[0];
  const float* emb = (const float*)d_in[1];

  float* out        = (float*)d_out;
  float* out_loss   = out;
  float* out_zq     = out + 1;
  float* out_perp   = out + 4194305;
  float* out_onehot = out + 4194306;
  float* out_idx    = out + 138412034;

  float* zsq      = (float*)d_ws;            // 16384 f
  float* esq      = zsq + NROWS;             // 8192 f
  u64*   best     = (u64*)(esq + NE);        // 16384 u64 (8B-aligned)
  int*   counts   = (int*)(best + NROWS);    // 8192 int
  float* partials = (float*)(counts + NE);   // 4096 f

  k_rowsq<<<96, 256, 0, stream>>>(z, emb, zsq, esq, best, counts);
  k_argmin<<<dim3(NROWS / TM, NCH), 256, 0, stream>>>(z, emb, zsq, esq, best,
                                                      out_onehot);
  k_gather2<<<NROWS / 4, 256, 0, stream>>>(z, emb, best, out_zq, out_onehot,
                                           out_idx, partials, counts);
  k_final<<<1, 256, 0, stream>>>(counts, partials, out_loss, out_perp);
}

// Round 12
// 1317.379 us; speedup vs baseline: 1.5015x; 1.2465x over previous
//
#include <hip/hip_runtime.h>
#include <cstddef>

#define NROWS 16384
#define NE    8192
#define DD    256
#define TM    256
#define TN    128
#define BK    16
#define NCH   8
#define CHW   (NE / NCH)   // 1024 cols per chunk

typedef unsigned long long u64;
typedef float vf4 __attribute__((ext_vector_type(4)));
typedef float vf2 __attribute__((ext_vector_type(2)));

#define OH_TOT ((size_t)NROWS * NE)           // 134217728 floats
#define OH_VEC ((OH_TOT - 4) / 4)             // 33554431 aligned vf4 slots

// ---------------------------------------------------------------------------
// k_rowsq: zsq[n] = sum(z[n,:]^2) in numpy pairwise order (256 = 128+128,
// each 128-block via 8 strided accumulators r[j] += x[8i+j]^2, combined
// pairwise). float4 loads (same add order as scalar). Also inits best[],
// counts.
// ---------------------------------------------------------------------------
__global__ __launch_bounds__(256) void k_rowsq(
    const float* __restrict__ z, const float* __restrict__ emb,
    float* __restrict__ zsq, float* __restrict__ esq,
    u64* __restrict__ best, int* __restrict__ counts)
{
  const int g = blockIdx.x * 256 + threadIdx.x;   // 0 .. 24575
  if (g < NE) counts[g] = 0;
  if (g < NROWS) best[g] = ~0ull;

  const float* row;
  float* outp;
  if (g < NROWS) { row = z + (size_t)g * DD;            outp = zsq + g; }
  else           { row = emb + (size_t)(g - NROWS) * DD; outp = esq + (g - NROWS); }

  float half_s[2];
#pragma unroll
  for (int h = 0; h < 2; ++h) {
    const float* p = row + h * 128;
    float r[8];
    {
      const float4 v0 = *(const float4*)(p);
      const float4 v1 = *(const float4*)(p + 4);
      const float xs[8] = {v0.x, v0.y, v0.z, v0.w, v1.x, v1.y, v1.z, v1.w};
#pragma unroll
      for (int j = 0; j < 8; ++j) {
        float sq = xs[j] * xs[j];
        asm volatile("" : "+v"(sq));   // block FMA contraction: np rounds x*x first
        r[j] = sq;
      }
    }
    for (int i = 8; i < 128; i += 8) {
      const float4 v0 = *(const float4*)(p + i);
      const float4 v1 = *(const float4*)(p + i + 4);
      const float xs[8] = {v0.x, v0.y, v0.z, v0.w, v1.x, v1.y, v1.z, v1.w};
#pragma unroll
      for (int j = 0; j < 8; ++j) {
        float sq = xs[j] * xs[j];
        asm volatile("" : "+v"(sq));
        r[j] = r[j] + sq;
      }
    }
    half_s[h] = ((r[0] + r[1]) + (r[2] + r[3])) + ((r[4] + r[5]) + (r[6] + r[7]));
  }
  *outp = half_s[0] + half_s[1];
}

// ---------------------------------------------------------------------------
// k_argmin v7 (restored from round 9 — best measured: 889 µs, VALUBusy 66%,
// 0 bank conflicts, no spills): 256x128 tile, 256 threads, 16x8 micro-tile,
// double-buffered LDS (A+B), fused nontemporal one-hot zero-fill riding the
// idle memory pipe, vf2 pk-fma accumulators.
// Numerics: ascending-k fused-FMA chain per (row,col), dv = fl(fl(zsq+esq)
// - 2*dot), u64 (bits(dv)<<32)|col atomicMin (d>0 -> order-preserving bits;
// lowest index wins ties) — bit-identical argmin decisions vs np reference.
// R6/R8/R10/R11 post-mortems: dbuf=neutral, pk=neutral, global-A=spills,
// uniform-A=conflicts+spills — this structure is the measured plateau.
// ---------------------------------------------------------------------------
__global__ __launch_bounds__(256)
__attribute__((amdgpu_waves_per_eu(2, 2)))
void k_argmin(
    const float* __restrict__ z, const float* __restrict__ emb,
    const float* __restrict__ zsq, const float* __restrict__ esq,
    u64* __restrict__ best, float* __restrict__ ohbase)
{
  __shared__ float As[2][BK][TM];       // 32 KB
  __shared__ float Bs[2][BK][TN];       // 16 KB

  const int tid = threadIdx.x;
  const int tx = tid & 15;
  const int ty = tid >> 4;
  const int tx4 = tx * 4;
  const int ty4 = ty * 4;
  const int R0 = blockIdx.x * TM;
  const int C0 = blockIdx.y * CHW;

  const int bcol = tid & 127;           // B staging col
  const int bk8  = (tid >> 7) * 8;      // B staging k-offset (0 or 8)

  const float* zrow = z + (size_t)(R0 + tid) * DD;

  // one-hot zero-fill state: flat block id owns vf4 slots [b*65536,(b+1)*65536)
  const int bflat = blockIdx.y * (NROWS / TM) + blockIdx.x;   // 0..511
  size_t zt = (size_t)bflat * 65536 + tid;                    // step 256, x256
  float* zp = ohbase + 2;                                     // 16B-aligned
  const vf4 zzero = {0.0f, 0.0f, 0.0f, 0.0f};
  if (bflat == 0 && tid == 0) { ohbase[0] = 0.0f; ohbase[1] = 0.0f; }
  if (bflat == 511 && tid == 0) { ohbase[OH_TOT - 2] = 0.0f; ohbase[OH_TOT - 1] = 0.0f; }

  u64 bp[16];
#pragma unroll
  for (int i = 0; i < 16; ++i) bp[i] = ~0ull;

#define STAGE(B_, K_)                                                     \
  {                                                                       \
    _Pragma("unroll")                                                     \
    for (int q = 0; q < 4; ++q) {                                         \
      const float4 v = *(const float4*)(zrow + (K_) + 4 * q);             \
      As[B_][4 * q + 0][tid] = v.x;                                       \
      As[B_][4 * q + 1][tid] = v.y;                                       \
      As[B_][4 * q + 2][tid] = v.z;                                       \
      As[B_][4 * q + 3][tid] = v.w;                                       \
    }                                                                     \
    _Pragma("unroll")                                                     \
    for (int h = 0; h < 2; ++h) {                                         \
      const float4 v = *(const float4*)(ecol + (K_) + 4 * h);             \
      Bs[B_][bk8 + 4 * h + 0][bcol] = v.x;                                \
      Bs[B_][bk8 + 4 * h + 1][bcol] = v.y;                                \
      Bs[B_][bk8 + 4 * h + 2][bcol] = v.z;                                \
      Bs[B_][bk8 + 4 * h + 3][bcol] = v.w;                                \
    }                                                                     \
    if (zt < OH_VEC) __builtin_nontemporal_store(zzero, (vf4*)(zp + 4 * zt)); \
    zt += 256;                                                            \
    if (zt < OH_VEC) __builtin_nontemporal_store(zzero, (vf4*)(zp + 4 * zt)); \
    zt += 256;                                                            \
  }

#define COMPUTE(B_)                                                       \
  _Pragma("unroll 2")                                                     \
  for (int kk = 0; kk < BK; ++kk) {                                       \
    const float4 a0 = *(const float4*)(&As[B_][kk][ty4]);                 \
    const float4 a1 = *(const float4*)(&As[B_][kk][ty4 + 64]);            \
    const float4 a2 = *(const float4*)(&As[B_][kk][ty4 + 128]);           \
    const float4 a3 = *(const float4*)(&As[B_][kk][ty4 + 192]);           \
    const float4 b0 = *(const float4*)(&Bs[B_][kk][tx4]);                 \
    const float4 b1 = *(const float4*)(&Bs[B_][kk][tx4 + 64]);            \
    const float av[16] = {a0.x, a0.y, a0.z, a0.w, a1.x, a1.y, a1.z, a1.w, \
                          a2.x, a2.y, a2.z, a2.w, a3.x, a3.y, a3.z, a3.w};\
    const vf2 b2[4] = {{b0.x, b0.y}, {b0.z, b0.w},                        \
                       {b1.x, b1.y}, {b1.z, b1.w}};                       \
    _Pragma("unroll")                                                     \
    for (int i = 0; i < 16; ++i) {                                        \
      const vf2 a2v = {av[i], av[i]};                                     \
      _Pragma("unroll")                                                   \
      for (int j = 0; j < 4; ++j)                                         \
        acc[i][j] = __builtin_elementwise_fma(a2v, b2[j], acc[i][j]);     \
    }                                                                     \
  }

  for (int t = 0; t < CHW; t += TN) {
    const int Cb = C0 + t;
    const float* ecol = emb + (size_t)(Cb + bcol) * DD + bk8;

    vf2 acc[16][4];   // [i][j2]: j2=0,1 -> cols tx4+0..3 ; j2=2,3 -> tx4+64..67
#pragma unroll
    for (int i = 0; i < 16; ++i)
#pragma unroll
      for (int j = 0; j < 4; ++j) acc[i][j] = (vf2){0.0f, 0.0f};

    STAGE(0, 0);
    __syncthreads();
    for (int c = 0; c < 16; c += 2) {
      if (c + 1 < 16) STAGE(1, (c + 1) * BK);
      COMPUTE(0);
      __syncthreads();
      if (c + 2 < 16) STAGE(0, (c + 2) * BK);
      COMPUTE(1);
      __syncthreads();
    }

#pragma unroll
    for (int j = 0; j < 8; ++j) {
      const int col = Cb + tx4 + ((j < 4) ? j : 64 + j - 4);
      const float ev = esq[col];
#pragma unroll
      for (int i = 0; i < 16; ++i) {
        const float zri = zsq[R0 + (i >> 2) * 64 + ty4 + (i & 3)];
        const float aij = acc[i][j >> 1][j & 1];
        const float s1 = zri + ev;                // fl(zsq+esq), matches np
        const float dv = s1 - 2.0f * aij;         // fl(s1 - 2*dot); 2*dot exact
        const u64 p = ((u64)__float_as_uint(dv) << 32) | (unsigned)col;
        if (p < bp[i]) bp[i] = p;
      }
    }
  }

#pragma unroll
  for (int i = 0; i < 16; ++i) {
#pragma unroll
    for (int off = 8; off > 0; off >>= 1) {
      const u64 o = __shfl_xor(bp[i], off, 16);
      if (o < bp[i]) bp[i] = o;
    }
  }
  if (tx == 0) {
#pragma unroll
    for (int i = 0; i < 16; ++i) {
      const int r = R0 + (i >> 2) * 64 + ty4 + (i & 3);
      atomicMin(&best[r], bp[i]);
    }
  }
}

// ---------------------------------------------------------------------------
// k_gather2: 4 rows per block. z_q gather, one-hot 1.0 scatter (zeros were
// laid down by k_argmin), float(index), counts, per-block loss partial.
// ---------------------------------------------------------------------------
__global__ __launch_bounds__(256) void k_gather2(
    const float* __restrict__ z, const float* __restrict__ emb,
    const u64* __restrict__ best,
    float* __restrict__ out_zq, float* __restrict__ out_onehot,
    float* __restrict__ out_idx, float* __restrict__ partials,
    int* __restrict__ counts)
{
  __shared__ float sred[256];
  const int row = blockIdx.x * 4 + (threadIdx.x >> 6);
  const int lane = threadIdx.x & 63;
  const int idx = (int)(unsigned)(best[row] & 0xffffffffull);
  const int k0 = lane * 4;

  const float4 e  = *(const float4*)(emb + (size_t)idx * DD + k0);
  const float4 zv = *(const float4*)(z + (size_t)row * DD + k0);
  *(float4*)(out_zq + (size_t)row * DD + k0) = e;

  const float dx = e.x - zv.x, dy = e.y - zv.y, dz = e.z - zv.z, dw = e.w - zv.w;
  sred[threadIdx.x] = dx * dx + dy * dy + dz * dz + dw * dw;

  if (lane == 0) {
    out_idx[row] = (float)idx;
    out_onehot[(size_t)row * NE + idx] = 1.0f;
    atomicAdd(&counts[idx], 1);
  }
  __syncthreads();
  for (int s = 128; s > 0; s >>= 1) {
    if (threadIdx.x < s) sred[threadIdx.x] += sred[threadIdx.x + s];
    __syncthreads();
  }
  if (threadIdx.x == 0) partials[blockIdx.x] = sred[0];
}

// ---------------------------------------------------------------------------
// k_final: loss = 1.25 * sum(partials) / (N*D); perplexity from counts.
// ---------------------------------------------------------------------------
__global__ __launch_bounds__(256) void k_final(
    const int* __restrict__ counts, const float* __restrict__ partials,
    float* __restrict__ out_loss, float* __restrict__ out_perp)
{
  __shared__ float sred[256];
  __shared__ float sl[256];
  float le = 0.0f;
  for (int e = threadIdx.x; e < NE; e += 256) {
    const float p = (float)counts[e] * (1.0f / 16384.0f);
    le += p * logf(p + 1e-10f);
  }
  float ll = 0.0f;
  for (int b = threadIdx.x; b < NROWS / 4; b += 256) ll += partials[b];
  sred[threadIdx.x] = le;
  sl[threadIdx.x] = ll;
  __syncthreads();
  for (int s = 128; s > 0; s >>= 1) {
    if (threadIdx.x < s) {
      sred[threadIdx.x] += sred[threadIdx.x + s];
      sl[threadIdx.x] += sl[threadIdx.x + s];
    }
    __syncthreads();
  }
  if (threadIdx.x == 0) {
    *out_perp = expf(-sred[0]);
    *out_loss = sl[0] * (1.25f / 4194304.0f);  // (1+beta) * sum / (N*D)
  }
}

// ---------------------------------------------------------------------------
// Output layout (float32, concatenated in reference return order):
//   [0]                loss                       (1)
//   [1 .. 4194304]     z_q_st                     (16384*256)
//   [4194305]          perplexity                 (1)
//   [4194306 ..]       min_encodings one-hot      (16384*8192)
//   [138412034 ..]     min_encoding_indices       (16384, written as float)
// ---------------------------------------------------------------------------
extern "C" void kernel_launch(void* const* d_in, const int* in_sizes, int n_in,
                              void* d_out, int out_size, void* d_ws, size_t ws_size,
                              hipStream_t stream) {
  const float* z   = (const float*)d_in[0];
  const float* emb = (const float*)d_in[1];

  float* out        = (float*)d_out;
  float* out_loss   = out;
  float* out_zq     = out + 1;
  float* out_perp   = out + 4194305;
  float* out_onehot = out + 4194306;
  float* out_idx    = out + 138412034;

  float* zsq      = (float*)d_ws;            // 16384 f
  float* esq      = zsq + NROWS;             // 8192 f
  u64*   best     = (u64*)(esq + NE);        // 16384 u64 (8B-aligned: offset 96 KB)
  int*   counts   = (int*)(best + NROWS);    // 8192 int
  float* partials = (float*)(counts + NE);   // 4096 f

  k_rowsq<<<96, 256, 0, stream>>>(z, emb, zsq, esq, best, counts);
  k_argmin<<<dim3(NROWS / TM, NCH), 256, 0, stream>>>(z, emb, zsq, esq, best,
                                                      out_onehot);
  k_gather2<<<NROWS / 4, 256, 0, stream>>>(z, emb, best, out_zq, out_onehot,
                                           out_idx, partials, counts);
  k_final<<<1, 256, 0, stream>>>(counts, partials, out_loss, out_perp);
}